// Round 9
// baseline (145.142 us; speedup 1.0000x reference)
//
#include <hip/hip_runtime.h>
#include <hip/hip_bf16.h>
#include <math.h>

typedef __attribute__((ext_vector_type(4)))  float f32x4;
typedef __attribute__((ext_vector_type(16))) float f32x16;
typedef __attribute__((ext_vector_type(8)))  short short8_t;
typedef __attribute__((ext_vector_type(4)))  short short4_t;

constexpr int Bn = 4, Hn = 16, Sn = 2048, Dn = 64;
constexpr int MW  = Sn / 64;   // packed-mask u64 words per row = 32
constexpr int NKT = Sn / 64;   // 64-key tiles = 32

__device__ __forceinline__ unsigned short f2bf(float f) {
    union { float f; unsigned u; } x; x.f = f;
    unsigned r = x.u + 0x7fffu + ((x.u >> 16) & 1u);  // RTNE
    return (unsigned short)(r >> 16);
}
__device__ __forceinline__ int sw8(int row) { return (row ^ (row >> 3)) & 7; }
__device__ __forceinline__ float exp2fast(float x) {
#if __has_builtin(__builtin_amdgcn_exp2f)
    return __builtin_amdgcn_exp2f(x);
#else
    float r; asm("v_exp_f32 %0, %1" : "=v"(r) : "v"(x)); return r;
#endif
}
__device__ __forceinline__ float max3f(float a, float b, float c) {
    return fmaxf(fmaxf(a, b), c);   // fuses to v_max3_f32
}
__device__ __forceinline__ f32x16 zero16() {
    f32x16 z;
#pragma unroll
    for (int i = 0; i < 16; ++i) z[i] = 0.f;
    return z;
}
__device__ __forceinline__ unsigned cvtpk(float lo, float hi_) {
    __hip_bfloat162 h2 = __float22bfloat162_rn(make_float2(lo, hi_));
    union { __hip_bfloat162 h; unsigned u; } u; u.h = h2;
    return u.u;
}
// v_permlane32_swap_b32: X' = [X_lo, Y_lo], Y' = [X_hi, Y_hi]
__device__ __forceinline__ void pswap(unsigned &x, unsigned &y) {
    asm("v_permlane32_swap_b32 %0, %1" : "+v"(x), "+v"(y));
}

// ================= prepass kernels =================
__global__ __launch_bounds__(256) void pack_mask(const void* __restrict__ Mp,
                                                 unsigned long long* __restrict__ PM) {
    unsigned accv = 0;
    {
        const unsigned* mw = (const unsigned*)Mp;
#pragma unroll
        for (int i = 0; i < 8; ++i) accv |= (mw[i] & 0xFFFFFF00u);
    }
    const bool i32 = (accv == 0u);
    const int lane = threadIdx.x & 63;
    const int wv = (int)((blockIdx.x * 256 + threadIdx.x) >> 6);   // 4096 waves
    const int w0 = wv * (Bn * Sn * MW / 4096);                     // 64 words/wave
    const int* mi32 = (const int*)Mp;
    const unsigned char* mu8 = (const unsigned char*)Mp;
    for (int j = 0; j < 64; j += 4) {
        int m0, m1, m2, m3;
        if (i32) {
            m0 = mi32[(size_t)(w0 + j) * 64 + lane];
            m1 = mi32[(size_t)(w0 + j + 1) * 64 + lane];
            m2 = mi32[(size_t)(w0 + j + 2) * 64 + lane];
            m3 = mi32[(size_t)(w0 + j + 3) * 64 + lane];
        } else {
            m0 = mu8[(size_t)(w0 + j) * 64 + lane];
            m1 = mu8[(size_t)(w0 + j + 1) * 64 + lane];
            m2 = mu8[(size_t)(w0 + j + 2) * 64 + lane];
            m3 = mu8[(size_t)(w0 + j + 3) * 64 + lane];
        }
        unsigned long long b0 = __ballot(m0 != 0);
        unsigned long long b1 = __ballot(m1 != 0);
        unsigned long long b2 = __ballot(m2 != 0);
        unsigned long long b3 = __ballot(m3 != 0);
        if (lane == 0) {
            PM[w0 + j] = b0; PM[w0 + j + 1] = b1;
            PM[w0 + j + 2] = b2; PM[w0 + j + 3] = b3;
        }
    }
}

// fused K->bf16 (linear) + V->bf16 transposed, one block per (bh, kt)
__global__ __launch_bounds__(256) void convKV(const float* __restrict__ K,
                                              const float* __restrict__ V,
                                              unsigned short* __restrict__ Kb,
                                              unsigned short* __restrict__ Vt) {
    __shared__ unsigned short tile[64 * 72];
    const int bh = blockIdx.x, kt = blockIdx.y, t = threadIdx.x;

    // ---- K: 64 rows x 64 d, straight bf16 convert ----
    {
        const float* ksrc = K + ((size_t)bh * Sn + kt * 64) * 64;
        unsigned short* kdst = Kb + ((size_t)bh * Sn + kt * 64) * 64;
#pragma unroll
        for (int j = 0; j < 2; ++j) {
            const int idx = j * 256 + t;       // 512 chunks of 8 floats
            f32x4 a = *(const f32x4*)(ksrc + idx * 8);
            f32x4 b = *(const f32x4*)(ksrc + idx * 8 + 4);
            short8_t h;
            h[0]=(short)f2bf(a[0]); h[1]=(short)f2bf(a[1]); h[2]=(short)f2bf(a[2]); h[3]=(short)f2bf(a[3]);
            h[4]=(short)f2bf(b[0]); h[5]=(short)f2bf(b[1]); h[6]=(short)f2bf(b[2]); h[7]=(short)f2bf(b[3]);
            *(short8_t*)(kdst + idx * 8) = h;
        }
    }

    // ---- V: transpose via LDS -> Vt[bh][v][k] ----
    {
        const int k = t >> 2, vq = (t & 3) * 16;
        const float* src = V + ((size_t)bh * Sn + kt * 64 + k) * 64 + vq;
#pragma unroll
        for (int j = 0; j < 4; ++j) {
            f32x4 f = *(const f32x4*)(src + j * 4);
            short4_t h;
            h[0]=(short)f2bf(f[0]); h[1]=(short)f2bf(f[1]); h[2]=(short)f2bf(f[2]); h[3]=(short)f2bf(f[3]);
            *(short4_t*)&tile[k * 72 + vq + j * 4] = h;
        }
        __syncthreads();
#pragma unroll
        for (int j = 0; j < 2; ++j) {
            const int v = (t >> 3) + 32 * j;
            const int oct = t & 7;
            short8_t h;
#pragma unroll
            for (int i2 = 0; i2 < 8; ++i2) h[i2] = (short)tile[(oct * 8 + i2) * 72 + v];
            *(short8_t*)(Vt + ((size_t)bh * 64 + v) * Sn + kt * 64 + oct * 8) = h;
        }
    }
}

// ====== main kernel (v7): two 32-key passes per tile -> one live score block,
//        total regs <= 128 -> 4 waves/SIMD (forced by launch_bounds) ======
__global__ __launch_bounds__(256, 4) void sdpa_v3(
    const float* __restrict__ Qp, const unsigned short* __restrict__ Kb,
    const unsigned short* __restrict__ Vt, const unsigned long long* __restrict__ PM,
    float* __restrict__ Op)
{
    __shared__ __align__(16) char smem[32768];
    unsigned short* smK = (unsigned short*)smem;            // [2][4096]
    unsigned short* smV = (unsigned short*)(smem + 16384);  // [2][4096]
    unsigned short* smQ = (unsigned short*)smem;            // prologue overlay [128][72]

    const int t = threadIdx.x;
    const int w = t >> 6;
    const int l = t & 63;
    const int ql = l & 31;
    const int hi = l >> 5;

    // XCD-aware remap (1024 blocks = 8 XCD * 128)
    const int gid = blockIdx.x;
    const int lin = (gid & 7) * 128 + (gid >> 3);
    const int bh = lin >> 4;
    const int qb = lin & 15;
    const int b = bh >> 4;
    const int q0 = qb * 128;

    const unsigned short* KbB = Kb + (size_t)bh * Sn * 64;
    const unsigned short* VtB = Vt + (size_t)bh * 64 * Sn;

    // ---- prologue: cooperative Q load -> smQ (bf16, scaled), then frags ----
    {
        const float qscale = 0.125f * 1.44269504088896340736f;  // 1/sqrt(64) * log2(e)
        const float* Qbase = Qp + ((size_t)bh * Sn + q0) * Dn;
#pragma unroll
        for (int j = 0; j < 8; ++j) {
            const int flat = j * 256 + t;           // 2048 f32x4 chunks
            const int row = flat >> 4, c4 = (flat & 15) * 4;
            f32x4 f = *(const f32x4*)(Qbase + (size_t)flat * 4);
            short4_t h;
            h[0]=(short)f2bf(f[0]*qscale); h[1]=(short)f2bf(f[1]*qscale);
            h[2]=(short)f2bf(f[2]*qscale); h[3]=(short)f2bf(f[3]*qscale);
            *(short4_t*)&smQ[row * 72 + c4] = h;
        }
    }
    __syncthreads();
    short8_t qf[4];
    {
        const int rowl = w * 32 + ql;
#pragma unroll
        for (int tt = 0; tt < 4; ++tt)
            qf[tt] = *(const short8_t*)&smQ[rowl * 72 + tt * 16 + hi * 8];
    }
    __syncthreads();

    // ---- staging: global_load_lds 16B, linear LDS dest, inverse-swizzled src ----
    auto stage = [&](int kt, int buf) {
        const int row = t >> 3, oct = t & 7;
        const int row2 = row + 32;
        {
            const unsigned short* g = KbB + ((size_t)(kt * 64 + row)) * 64 + (oct ^ sw8(row)) * 8;
            __builtin_amdgcn_global_load_lds((const __attribute__((address_space(1))) unsigned int*)g,
                (__attribute__((address_space(3))) unsigned int*)(smK + buf * 4096 + t * 8), 16, 0, 0);
            const unsigned short* g2 = KbB + ((size_t)(kt * 64 + row2)) * 64 + (oct ^ sw8(row2)) * 8;
            __builtin_amdgcn_global_load_lds((const __attribute__((address_space(1))) unsigned int*)g2,
                (__attribute__((address_space(3))) unsigned int*)(smK + buf * 4096 + 2048 + t * 8), 16, 0, 0);
        }
        {
            const unsigned short* g = VtB + (size_t)row * Sn + kt * 64 + (oct ^ sw8(row)) * 8;
            __builtin_amdgcn_global_load_lds((const __attribute__((address_space(1))) unsigned int*)g,
                (__attribute__((address_space(3))) unsigned int*)(smV + buf * 4096 + t * 8), 16, 0, 0);
            const unsigned short* g2 = VtB + (size_t)row2 * Sn + kt * 64 + (oct ^ sw8(row2)) * 8;
            __builtin_amdgcn_global_load_lds((const __attribute__((address_space(1))) unsigned int*)g2,
                (__attribute__((address_space(3))) unsigned int*)(smV + buf * 4096 + 2048 + t * 8), 16, 0, 0);
        }
    };
    auto ldf = [&](const unsigned short* base, int row, int olog) -> short8_t {
        return *(const short8_t*)(base + row * 64 + (olog ^ sw8(row)) * 8);
    };

    f32x16 o0 = zero16(), o1 = zero16();
    float m_run = -INFINITY, l_run = 0.f;
    const int qrow = q0 + w * 32 + ql;
    const unsigned long long* pmrow = PM + ((size_t)b * Sn + qrow) * MW;

    stage(0, 0);
    __syncthreads();

    for (int kt = 0; kt < NKT; ++kt) {
        const int cur = kt & 1;
        if (kt + 1 < NKT) stage(kt + 1, cur ^ 1);
        const unsigned long long bits = pmrow[kt];
        const unsigned short* bK = smK + cur * 4096;
        const unsigned short* bV = smV + cur * 4096;

#pragma unroll
        for (int h = 0; h < 2; ++h) {
            // ---- QK^T (swapped): 32 keys of this half, lane q = ql ----
            f32x16 s = zero16();
            __builtin_amdgcn_s_setprio(1);
#pragma unroll
            for (int tt = 0; tt < 4; ++tt) {
                short8_t a0 = ldf(bK, 32 * h + ql, 2 * tt + hi);
                s = __builtin_amdgcn_mfma_f32_32x32x16_bf16(a0, qf[tt], s, 0, 0, 0);
            }
            __builtin_amdgcn_s_setprio(0);

            // ---- mask (reg r: key = 32h + (r&3) + 8*(r>>2) + 4*hi) ----
            const unsigned w32 = (unsigned)(bits >> (32 * h)) >> (hi * 4);
#pragma unroll
            for (int r = 0; r < 16; ++r) {
                const int bp = 8 * (r >> 2) + (r & 3);
                s[r] = ((w32 >> bp) & 1u) ? -1e9f : s[r];
            }

            // ---- online max (v_max3 chain), lane-local q-row ----
            float mx = fmaxf(s[0], s[1]);
#pragma unroll
            for (int r = 2; r < 16; r += 2) mx = max3f(mx, s[r], s[r + 1]);
            mx = fmaxf(mx, __shfl_xor(mx, 32));

            if (!__all(mx - m_run <= 8.0f)) {   // defer-max (THR=8, log2 domain)
                const float mn = fmaxf(m_run, mx);
                const float corr = exp2fast(m_run - mn);
                m_run = mn;
                l_run *= corr;
#pragma unroll
                for (int r = 0; r < 16; ++r) {
                    const int qloc = (r & 3) + 8 * (r >> 2) + 4 * hi;
                    const float cr = __shfl(corr, qloc);
                    o0[r] *= cr; o1[r] *= cr;
                }
            }
#pragma unroll
            for (int r = 0; r < 16; ++r) s[r] = exp2fast(s[r] - m_run);

            // ---- l: tree sum + cross-half combine (round-6-proven pattern) ----
            {
                float p0 = 0.f, p1 = 0.f, p2 = 0.f, p3 = 0.f;
#pragma unroll
                for (int r = 0; r < 16; r += 4) {
                    p0 += s[r]; p1 += s[r + 1]; p2 += s[r + 2]; p3 += s[r + 3];
                }
                float rs = (p0 + p1) + (p2 + p3);
                rs += __shfl_xor(rs, 32);
                l_run += rs;
            }

            // ---- PV: fused cvt+permlane+MFMA per 16-key slice ----
            __builtin_amdgcn_s_setprio(1);
#pragma unroll
            for (int ksl = 0; ksl < 2; ++ksl) {
                const int off = ksl * 8;
                unsigned x0 = cvtpk(s[off],     s[off + 1]);
                unsigned x1 = cvtpk(s[off + 2], s[off + 3]);
                unsigned y0 = cvtpk(s[off + 4], s[off + 5]);
                unsigned y1 = cvtpk(s[off + 6], s[off + 7]);
                pswap(x0, y0);   // x0' = frag word0, y0' = frag word2
                pswap(x1, y1);   // x1' = frag word1, y1' = frag word3
                union { unsigned u[4]; short8_t v; } pa;
                pa.u[0] = x0; pa.u[1] = x1; pa.u[2] = y0; pa.u[3] = y1;
                const int ksg = 2 * h + ksl;
                short8_t vf0 = ldf(bV, ql,      2 * ksg + hi);
                short8_t vf1 = ldf(bV, 32 + ql, 2 * ksg + hi);
                o0 = __builtin_amdgcn_mfma_f32_32x32x16_bf16(pa.v, vf0, o0, 0, 0, 0);
                o1 = __builtin_amdgcn_mfma_f32_32x32x16_bf16(pa.v, vf1, o1, 0, 0, 0);
            }
            __builtin_amdgcn_s_setprio(0);
        }
        __syncthreads();   // drains gload_lds (next tile) + guards buffer reuse
    }

    // ---- epilogue: 1/l redistribution via shfl, store fp32 ----
    const float inv = 1.0f / l_run;
#pragma unroll
    for (int r = 0; r < 16; ++r) {
        const int qloc = (r & 3) + 8 * (r >> 2) + 4 * hi;
        const float iv = __shfl(inv, qloc);
        float* orow = Op + ((size_t)bh * Sn + q0 + w * 32 + qloc) * 64;
        orow[ql] = o0[r] * iv;
        orow[32 + ql] = o1[r] * iv;
    }
}

// ================= fallback (round-2 kernel, proven) =================
__global__ __launch_bounds__(512, 4) void sdpa_v2(
    const float* __restrict__ Qp, const float* __restrict__ Kp,
    const float* __restrict__ Vp, const void* __restrict__ Mp,
    const unsigned long long* __restrict__ PM, float* __restrict__ Op)
{
    __shared__ unsigned short lds_k[64 * 64];
    __shared__ unsigned short lds_vt[64 * 64];
    __shared__ unsigned short lds_p[8][16 * 64];

    const int t = threadIdx.x;
    const int wave = t >> 6;
    const int lane = t & 63;
    const int g = lane >> 4;
    const int c = lane & 15;

    const int gid = blockIdx.x;
    const int lin = (gid & 7) * 128 + (gid >> 3);
    const int bh = lin >> 4;
    const int qb = lin & 15;
    const int b = bh >> 4;
    const int q0 = qb * 128;

    bool m_i32 = true;
    if (!PM) {
        unsigned accv = 0;
        const unsigned* mw = (const unsigned*)Mp;
#pragma unroll
        for (int i = 0; i < 32; ++i) accv |= (mw[i] & 0xFFFFFF00u);
        m_i32 = (accv == 0u);
    }
    const int* mi32 = (const int*)Mp;
    const unsigned char* mu8 = (const unsigned char*)Mp;

    short8_t qf[2];
    {
        const float qscale = 0.125f * 1.44269504088896340736f;
        const float* qsrc = Qp + ((size_t)bh * Sn + q0 + wave * 16 + c) * Dn + g * 8;
#pragma unroll
        for (int h2 = 0; h2 < 2; ++h2) {
            f32x4 f0 = *(const f32x4*)(qsrc + h2 * 32);
            f32x4 f1 = *(const f32x4*)(qsrc + h2 * 32 + 4);
            short8_t v;
            v[0]=(short)f2bf(f0[0]*qscale); v[1]=(short)f2bf(f0[1]*qscale);
            v[2]=(short)f2bf(f0[2]*qscale); v[3]=(short)f2bf(f0[3]*qscale);
            v[4]=(short)f2bf(f1[0]*qscale); v[5]=(short)f2bf(f1[1]*qscale);
            v[6]=(short)f2bf(f1[2]*qscale); v[7]=(short)f2bf(f1[3]*qscale);
            qf[h2] = v;
        }
    }

    f32x4 o[4];
#pragma unroll
    for (int i = 0; i < 4; ++i) o[i] = (f32x4){0.f, 0.f, 0.f, 0.f};
    float m_run[4] = {-INFINITY, -INFINITY, -INFINITY, -INFINITY};
    float l_run[4] = {0.f, 0.f, 0.f, 0.f};

    const float* kbase = Kp + (size_t)bh * Sn * Dn;
    const float* vbase = Vp + (size_t)bh * Sn * Dn;
    const size_t mrow0 = (size_t)b * Sn + q0 + wave * 16 + g * 4;

    for (int kt = 0; kt < NKT; ++kt) {
        const int k0 = kt * 64;
        {
            const int key = t >> 3;
            const int d0 = (t & 7) * 8;
            const float* src = kbase + (size_t)(k0 + key) * Dn + d0;
            f32x4 f0 = *(const f32x4*)src;
            f32x4 f1 = *(const f32x4*)(src + 4);
            short8_t hv;
            hv[0]=(short)f2bf(f0[0]); hv[1]=(short)f2bf(f0[1]);
            hv[2]=(short)f2bf(f0[2]); hv[3]=(short)f2bf(f0[3]);
            hv[4]=(short)f2bf(f1[0]); hv[5]=(short)f2bf(f1[1]);
            hv[6]=(short)f2bf(f1[2]); hv[7]=(short)f2bf(f1[3]);
            *(short8_t*)&lds_k[key * 64 + (d0 ^ (sw8(key) << 3))] = hv;
        }
        {
            const int vv = t & 63;
            const int kq = (t >> 6) * 8;
            short8_t hv;
#pragma unroll
            for (int j = 0; j < 8; ++j)
                hv[j] = (short)f2bf(vbase[(size_t)(k0 + kq + j) * Dn + vv]);
            *(short8_t*)&lds_vt[vv * 64 + (kq ^ (sw8(vv) << 3))] = hv;
        }
        __syncthreads();

        f32x4 s[4];
#pragma unroll
        for (int e = 0; e < 4; ++e) s[e] = (f32x4){0.f, 0.f, 0.f, 0.f};
        __builtin_amdgcn_s_setprio(1);
#pragma unroll
        for (int e = 0; e < 4; ++e) {
            const int ke = e * 16 + c;
            const int swk = sw8(ke) << 3;
            short8_t kf0 = *(const short8_t*)&lds_k[ke * 64 + ((g * 8) ^ swk)];
            short8_t kf1 = *(const short8_t*)&lds_k[ke * 64 + ((32 + g * 8) ^ swk)];
            s[e] = __builtin_amdgcn_mfma_f32_16x16x32_bf16(qf[0], kf0, s[e], 0, 0, 0);
            s[e] = __builtin_amdgcn_mfma_f32_16x16x32_bf16(qf[1], kf1, s[e], 0, 0, 0);
        }
        __builtin_amdgcn_s_setprio(0);

        unsigned long long bits[4];
        if (PM) {
#pragma unroll
            for (int r = 0; r < 4; ++r) bits[r] = PM[(mrow0 + r) * MW + kt];
        } else {
#pragma unroll
            for (int r = 0; r < 4; ++r) {
                const size_t mi = (mrow0 + r) * Sn + k0 + c;
                unsigned long long bbv = 0;
#pragma unroll
                for (int e = 0; e < 4; ++e) {
                    int mm = m_i32 ? mi32[mi + 16 * e] : (int)mu8[mi + 16 * e];
                    bbv |= (unsigned long long)(mm != 0) << (c + 16 * e);
                }
                bits[r] = bbv;
            }
        }

        float p[4][4], mx[4];
#pragma unroll
        for (int r = 0; r < 4; ++r) {
            const unsigned lo = (unsigned)bits[r];
            const unsigned hh = (unsigned)(bits[r] >> 32);
            const unsigned t0 = lo >> c;
            const unsigned t1 = hh >> c;
            float v0 = (t0 & 1u)       ? -1e9f : s[0][r];
            float v1 = (t0 & 0x10000u) ? -1e9f : s[1][r];
            float v2 = (t1 & 1u)       ? -1e9f : s[2][r];
            float v3 = (t1 & 0x10000u) ? -1e9f : s[3][r];
            p[0][r] = v0; p[1][r] = v1; p[2][r] = v2; p[3][r] = v3;
            mx[r] = fmaxf(fmaxf(v0, v1), fmaxf(v2, v3));
        }
#pragma unroll
        for (int sh = 1; sh < 16; sh <<= 1) {
#pragma unroll
            for (int r = 0; r < 4; ++r) mx[r] = fmaxf(mx[r], __shfl_xor(mx[r], sh));
        }
        float need = mx[0] - m_run[0];
        need = fmaxf(need, mx[1] - m_run[1]);
        need = fmaxf(need, mx[2] - m_run[2]);
        need = fmaxf(need, mx[3] - m_run[3]);
        if (!__all(need <= 8.0f)) {
#pragma unroll
            for (int r = 0; r < 4; ++r) {
                const float mn = fmaxf(m_run[r], mx[r]);
                const float corr = exp2fast(m_run[r] - mn);
                m_run[r] = mn;
                l_run[r] *= corr;
#pragma unroll
                for (int cg = 0; cg < 4; ++cg) o[cg][r] *= corr;
            }
        }
        float rsv[4];
#pragma unroll
        for (int r = 0; r < 4; ++r) {
            p[0][r] = exp2fast(p[0][r] - m_run[r]);
            p[1][r] = exp2fast(p[1][r] - m_run[r]);
            p[2][r] = exp2fast(p[2][r] - m_run[r]);
            p[3][r] = exp2fast(p[3][r] - m_run[r]);
            rsv[r] = (p[0][r] + p[1][r]) + (p[2][r] + p[3][r]);
        }
#pragma unroll
        for (int sh = 1; sh < 16; sh <<= 1) {
#pragma unroll
            for (int r = 0; r < 4; ++r) rsv[r] += __shfl_xor(rsv[r], sh);
        }
#pragma unroll
        for (int r = 0; r < 4; ++r) l_run[r] += rsv[r];

        unsigned short* pw = lds_p[wave];
#pragma unroll
        for (int r = 0; r < 4; ++r) {
            const int row = g * 4 + r;
            const int swp = sw8(row) << 3;
            pw[row * 64 + ((c)      ^ swp)] = f2bf(p[0][r]);
            pw[row * 64 + ((c + 16) ^ swp)] = f2bf(p[1][r]);
            pw[row * 64 + ((c + 32) ^ swp)] = f2bf(p[2][r]);
            pw[row * 64 + ((c + 48) ^ swp)] = f2bf(p[3][r]);
        }
        const int swc = sw8(c) << 3;
        const short8_t pf0 = *(const short8_t*)&pw[c * 64 + ((g * 8) ^ swc)];
        const short8_t pf1 = *(const short8_t*)&pw[c * 64 + ((32 + g * 8) ^ swc)];
        __builtin_amdgcn_s_setprio(1);
#pragma unroll
        for (int cg = 0; cg < 4; ++cg) {
            const int vv = cg * 16 + c;
            const int swv = sw8(vv) << 3;
            const short8_t vf0 = *(const short8_t*)&lds_vt[vv * 64 + ((g * 8) ^ swv)];
            const short8_t vf1 = *(const short8_t*)&lds_vt[vv * 64 + ((32 + g * 8) ^ swv)];
            o[cg] = __builtin_amdgcn_mfma_f32_16x16x32_bf16(pf0, vf0, o[cg], 0, 0, 0);
            o[cg] = __builtin_amdgcn_mfma_f32_16x16x32_bf16(pf1, vf1, o[cg], 0, 0, 0);
        }
        __builtin_amdgcn_s_setprio(0);
        __syncthreads();
    }

#pragma unroll
    for (int r = 0; r < 4; ++r) {
        const float inv = 1.0f / l_run[r];
        float* orow = Op + ((size_t)bh * Sn + q0 + wave * 16 + g * 4 + r) * Dn + c;
#pragma unroll
        for (int cg = 0; cg < 4; ++cg) orow[cg * 16] = o[cg][r] * inv;
    }
}

extern "C" void kernel_launch(void* const* d_in, const int* in_sizes, int n_in,
                              void* d_out, int out_size, void* d_ws, size_t ws_size,
                              hipStream_t stream) {
    (void)in_sizes; (void)n_in; (void)out_size;
    const float* Q = (const float*)d_in[0];
    const float* K = (const float*)d_in[1];
    const float* V = (const float*)d_in[2];
    const void*  M = d_in[3];
    float* O = (float*)d_out;

    const size_t pmB = (size_t)Bn * Sn * MW * 8;            // 2 MB packed mask
    const size_t kvB = (size_t)Bn * Hn * Sn * Dn * 2;       // 16.78 MB each

    if (ws_size >= pmB + 2 * kvB) {
        unsigned long long* PM = (unsigned long long*)d_ws;
        unsigned short* Kb = (unsigned short*)((char*)d_ws + pmB);
        unsigned short* Vt = (unsigned short*)((char*)d_ws + pmB + kvB);
        pack_mask<<<1024, 256, 0, stream>>>(M, PM);
        convKV<<<dim3(Bn * Hn, NKT), 256, 0, stream>>>(K, V, Kb, Vt);
        sdpa_v3<<<dim3(1024), dim3(256), 0, stream>>>(Q, Kb, Vt, PM, O);
    } else {
        unsigned long long* PM = nullptr;
        if (ws_size >= pmB) {
            PM = (unsigned long long*)d_ws;
            pack_mask<<<1024, 256, 0, stream>>>(M, PM);
        }
        sdpa_v2<<<dim3(1024), dim3(512), 0, stream>>>(Q, K, V, M, PM, O);
    }
}

// Round 11
// 143.084 us; speedup vs baseline: 1.0144x; 1.0144x over previous
//
#include <hip/hip_runtime.h>
#include <hip/hip_bf16.h>
#include <math.h>

typedef __attribute__((ext_vector_type(4)))  float f32x4;
typedef __attribute__((ext_vector_type(16))) float f32x16;
typedef __attribute__((ext_vector_type(8)))  short short8_t;
typedef __attribute__((ext_vector_type(4)))  short short4_t;

constexpr int Bn = 4, Hn = 16, Sn = 2048, Dn = 64;
constexpr int MW  = Sn / 64;   // packed-mask u64 words per row = 32
constexpr int NKT = Sn / 64;   // 64-key tiles = 32

__device__ __forceinline__ unsigned short f2bf(float f) {
    union { float f; unsigned u; } x; x.f = f;
    unsigned r = x.u + 0x7fffu + ((x.u >> 16) & 1u);  // RTNE
    return (unsigned short)(r >> 16);
}
__device__ __forceinline__ int sw8(int row) { return (row ^ (row >> 3)) & 7; }
__device__ __forceinline__ float exp2fast(float x) {
#if __has_builtin(__builtin_amdgcn_exp2f)
    return __builtin_amdgcn_exp2f(x);
#else
    float r; asm("v_exp_f32 %0, %1" : "=v"(r) : "v"(x)); return r;
#endif
}
__device__ __forceinline__ float max3f(float a, float b, float c) {
    return fmaxf(fmaxf(a, b), c);   // fuses to v_max3_f32
}
__device__ __forceinline__ f32x16 zero16() {
    f32x16 z;
#pragma unroll
    for (int i = 0; i < 16; ++i) z[i] = 0.f;
    return z;
}
__device__ __forceinline__ unsigned cvtpk(float lo, float hi_) {
    __hip_bfloat162 h2 = __float22bfloat162_rn(make_float2(lo, hi_));
    union { __hip_bfloat162 h; unsigned u; } u; u.h = h2;
    return u.u;
}
// v_permlane32_swap_b32: X' = [X_lo, Y_lo], Y' = [X_hi, Y_hi]
__device__ __forceinline__ void pswap(unsigned &x, unsigned &y) {
    asm("v_permlane32_swap_b32 %0, %1" : "+v"(x), "+v"(y));
}

// ================= prepass kernels =================
// standalone pack_mask kept for the no-workspace fallback path
__global__ __launch_bounds__(256) void pack_mask(const void* __restrict__ Mp,
                                                 unsigned long long* __restrict__ PM) {
    unsigned accv = 0;
    {
        const unsigned* mw = (const unsigned*)Mp;
#pragma unroll
        for (int i = 0; i < 8; ++i) accv |= (mw[i] & 0xFFFFFF00u);
    }
    const bool i32 = (accv == 0u);
    const int lane = threadIdx.x & 63;
    const int wv = (int)((blockIdx.x * 256 + threadIdx.x) >> 6);   // 4096 waves
    const int w0 = wv * (Bn * Sn * MW / 4096);                     // 64 words/wave
    const int* mi32 = (const int*)Mp;
    const unsigned char* mu8 = (const unsigned char*)Mp;
    for (int j = 0; j < 64; j += 4) {
        int m0, m1, m2, m3;
        if (i32) {
            m0 = mi32[(size_t)(w0 + j) * 64 + lane];
            m1 = mi32[(size_t)(w0 + j + 1) * 64 + lane];
            m2 = mi32[(size_t)(w0 + j + 2) * 64 + lane];
            m3 = mi32[(size_t)(w0 + j + 3) * 64 + lane];
        } else {
            m0 = mu8[(size_t)(w0 + j) * 64 + lane];
            m1 = mu8[(size_t)(w0 + j + 1) * 64 + lane];
            m2 = mu8[(size_t)(w0 + j + 2) * 64 + lane];
            m3 = mu8[(size_t)(w0 + j + 3) * 64 + lane];
        }
        unsigned long long b0 = __ballot(m0 != 0);
        unsigned long long b1 = __ballot(m1 != 0);
        unsigned long long b2 = __ballot(m2 != 0);
        unsigned long long b3 = __ballot(m3 != 0);
        if (lane == 0) {
            PM[w0 + j] = b0; PM[w0 + j + 1] = b1;
            PM[w0 + j + 2] = b2; PM[w0 + j + 3] = b3;
        }
    }
}

// fused prepass: K->bf16 (linear) + V->bf16 transposed + this block's 128 mask
// words packed to bits. One block per (bh, kt); 2048 blocks cover the
// 262144-word mask exactly (128 words/block).
__global__ __launch_bounds__(256) void convKV(const float* __restrict__ K,
                                              const float* __restrict__ V,
                                              const void* __restrict__ Mp,
                                              unsigned short* __restrict__ Kb,
                                              unsigned short* __restrict__ Vt,
                                              unsigned long long* __restrict__ PM) {
    __shared__ unsigned short tile[64 * 72];
    const int bh = blockIdx.x, kt = blockIdx.y, t = threadIdx.x;

    // ---- K: 64 rows x 64 d, straight bf16 convert ----
    {
        const float* ksrc = K + ((size_t)bh * Sn + kt * 64) * 64;
        unsigned short* kdst = Kb + ((size_t)bh * Sn + kt * 64) * 64;
#pragma unroll
        for (int j = 0; j < 2; ++j) {
            const int idx = j * 256 + t;       // 512 chunks of 8 floats
            f32x4 a = *(const f32x4*)(ksrc + idx * 8);
            f32x4 b = *(const f32x4*)(ksrc + idx * 8 + 4);
            short8_t h;
            h[0]=(short)f2bf(a[0]); h[1]=(short)f2bf(a[1]); h[2]=(short)f2bf(a[2]); h[3]=(short)f2bf(a[3]);
            h[4]=(short)f2bf(b[0]); h[5]=(short)f2bf(b[1]); h[6]=(short)f2bf(b[2]); h[7]=(short)f2bf(b[3]);
            *(short8_t*)(kdst + idx * 8) = h;
        }
    }

    // ---- mask pack: 128 u64 words for this block (32 per wave) ----
    {
        unsigned accv = 0;
        const unsigned* mw = (const unsigned*)Mp;
#pragma unroll
        for (int i = 0; i < 8; ++i) accv |= (mw[i] & 0xFFFFFF00u);
        const bool i32 = (accv == 0u);
        const int wv = t >> 6, lane = t & 63;
        const int base = (bh * NKT + kt) * 128 + wv * 32;
        const int* mi32 = (const int*)Mp;
        const unsigned char* mu8 = (const unsigned char*)Mp;
#pragma unroll 4
        for (int j = 0; j < 32; ++j) {
            int m = i32 ? mi32[(size_t)(base + j) * 64 + lane]
                        : (int)mu8[(size_t)(base + j) * 64 + lane];
            unsigned long long bal = __ballot(m != 0);
            if (lane == 0) PM[base + j] = bal;
        }
    }

    // ---- V: transpose via LDS -> Vt[bh][v][k] ----
    {
        const int k = t >> 2, vq = (t & 3) * 16;
        const float* src = V + ((size_t)bh * Sn + kt * 64 + k) * 64 + vq;
#pragma unroll
        for (int j = 0; j < 4; ++j) {
            f32x4 f = *(const f32x4*)(src + j * 4);
            short4_t h;
            h[0]=(short)f2bf(f[0]); h[1]=(short)f2bf(f[1]); h[2]=(short)f2bf(f[2]); h[3]=(short)f2bf(f[3]);
            *(short4_t*)&tile[k * 72 + vq + j * 4] = h;
        }
        __syncthreads();
#pragma unroll
        for (int j = 0; j < 2; ++j) {
            const int v = (t >> 3) + 32 * j;
            const int oct = t & 7;
            short8_t h;
#pragma unroll
            for (int i2 = 0; i2 < 8; ++i2) h[i2] = (short)tile[(oct * 8 + i2) * 72 + v];
            *(short8_t*)(Vt + ((size_t)bh * 64 + v) * Sn + kt * 64 + oct * 8) = h;
        }
    }
}

// ====== main kernel (round-9 proven): two 32-key passes per tile, 64 VGPR,
//        __syncthreads-fenced double buffer ======
__global__ __launch_bounds__(256, 4) void sdpa_v3(
    const float* __restrict__ Qp, const unsigned short* __restrict__ Kb,
    const unsigned short* __restrict__ Vt, const unsigned long long* __restrict__ PM,
    float* __restrict__ Op)
{
    __shared__ __align__(16) char smem[32768];
    unsigned short* smK = (unsigned short*)smem;            // [2][4096]
    unsigned short* smV = (unsigned short*)(smem + 16384);  // [2][4096]
    unsigned short* smQ = (unsigned short*)smem;            // prologue overlay [128][72]

    const int t = threadIdx.x;
    const int w = t >> 6;
    const int l = t & 63;
    const int ql = l & 31;
    const int hi = l >> 5;

    // XCD-aware remap (1024 blocks = 8 XCD * 128)
    const int gid = blockIdx.x;
    const int lin = (gid & 7) * 128 + (gid >> 3);
    const int bh = lin >> 4;
    const int qb = lin & 15;
    const int b = bh >> 4;
    const int q0 = qb * 128;

    const unsigned short* KbB = Kb + (size_t)bh * Sn * 64;
    const unsigned short* VtB = Vt + (size_t)bh * 64 * Sn;

    // ---- prologue: cooperative Q load -> smQ (bf16, scaled), then frags ----
    {
        const float qscale = 0.125f * 1.44269504088896340736f;  // 1/sqrt(64) * log2(e)
        const float* Qbase = Qp + ((size_t)bh * Sn + q0) * Dn;
#pragma unroll
        for (int j = 0; j < 8; ++j) {
            const int flat = j * 256 + t;           // 2048 f32x4 chunks
            const int row = flat >> 4, c4 = (flat & 15) * 4;
            f32x4 f = *(const f32x4*)(Qbase + (size_t)flat * 4);
            short4_t h;
            h[0]=(short)f2bf(f[0]*qscale); h[1]=(short)f2bf(f[1]*qscale);
            h[2]=(short)f2bf(f[2]*qscale); h[3]=(short)f2bf(f[3]*qscale);
            *(short4_t*)&smQ[row * 72 + c4] = h;
        }
    }
    __syncthreads();
    short8_t qf[4];
    {
        const int rowl = w * 32 + ql;
#pragma unroll
        for (int tt = 0; tt < 4; ++tt)
            qf[tt] = *(const short8_t*)&smQ[rowl * 72 + tt * 16 + hi * 8];
    }
    __syncthreads();

    // ---- staging: global_load_lds 16B, linear LDS dest, inverse-swizzled src ----
    auto stage = [&](int kt, int buf) {
        const int row = t >> 3, oct = t & 7;
        const int row2 = row + 32;
        {
            const unsigned short* g = KbB + ((size_t)(kt * 64 + row)) * 64 + (oct ^ sw8(row)) * 8;
            __builtin_amdgcn_global_load_lds((const __attribute__((address_space(1))) unsigned int*)g,
                (__attribute__((address_space(3))) unsigned int*)(smK + buf * 4096 + t * 8), 16, 0, 0);
            const unsigned short* g2 = KbB + ((size_t)(kt * 64 + row2)) * 64 + (oct ^ sw8(row2)) * 8;
            __builtin_amdgcn_global_load_lds((const __attribute__((address_space(1))) unsigned int*)g2,
                (__attribute__((address_space(3))) unsigned int*)(smK + buf * 4096 + 2048 + t * 8), 16, 0, 0);
        }
        {
            const unsigned short* g = VtB + (size_t)row * Sn + kt * 64 + (oct ^ sw8(row)) * 8;
            __builtin_amdgcn_global_load_lds((const __attribute__((address_space(1))) unsigned int*)g,
                (__attribute__((address_space(3))) unsigned int*)(smV + buf * 4096 + t * 8), 16, 0, 0);
            const unsigned short* g2 = VtB + (size_t)row2 * Sn + kt * 64 + (oct ^ sw8(row2)) * 8;
            __builtin_amdgcn_global_load_lds((const __attribute__((address_space(1))) unsigned int*)g2,
                (__attribute__((address_space(3))) unsigned int*)(smV + buf * 4096 + 2048 + t * 8), 16, 0, 0);
        }
    };
    auto ldf = [&](const unsigned short* base, int row, int olog) -> short8_t {
        return *(const short8_t*)(base + row * 64 + (olog ^ sw8(row)) * 8);
    };

    f32x16 o0 = zero16(), o1 = zero16();
    float m_run = -INFINITY, l_run = 0.f;
    const int qrow = q0 + w * 32 + ql;
    const unsigned long long* pmrow = PM + ((size_t)b * Sn + qrow) * MW;

    stage(0, 0);
    __syncthreads();

    for (int kt = 0; kt < NKT; ++kt) {
        const int cur = kt & 1;
        if (kt + 1 < NKT) stage(kt + 1, cur ^ 1);
        const unsigned long long bits = pmrow[kt];
        const unsigned short* bK = smK + cur * 4096;
        const unsigned short* bV = smV + cur * 4096;

#pragma unroll
        for (int h = 0; h < 2; ++h) {
            // ---- QK^T (swapped): 32 keys of this half, lane q = ql ----
            f32x16 s = zero16();
            __builtin_amdgcn_s_setprio(1);
#pragma unroll
            for (int tt = 0; tt < 4; ++tt) {
                short8_t a0 = ldf(bK, 32 * h + ql, 2 * tt + hi);
                s = __builtin_amdgcn_mfma_f32_32x32x16_bf16(a0, qf[tt], s, 0, 0, 0);
            }
            __builtin_amdgcn_s_setprio(0);

            // ---- mask (reg r: key = 32h + (r&3) + 8*(r>>2) + 4*hi) ----
            const unsigned w32 = (unsigned)(bits >> (32 * h)) >> (hi * 4);
#pragma unroll
            for (int r = 0; r < 16; ++r) {
                const int bp = 8 * (r >> 2) + (r & 3);
                s[r] = ((w32 >> bp) & 1u) ? -1e9f : s[r];
            }

            // ---- online max (v_max3 chain), lane-local q-row ----
            float mx = fmaxf(s[0], s[1]);
#pragma unroll
            for (int r = 2; r < 16; r += 2) mx = max3f(mx, s[r], s[r + 1]);
            mx = fmaxf(mx, __shfl_xor(mx, 32));

            if (!__all(mx - m_run <= 8.0f)) {   // defer-max (THR=8, log2 domain)
                const float mn = fmaxf(m_run, mx);
                const float corr = exp2fast(m_run - mn);
                m_run = mn;
                l_run *= corr;
#pragma unroll
                for (int r = 0; r < 16; ++r) {
                    const int qloc = (r & 3) + 8 * (r >> 2) + 4 * hi;
                    const float cr = __shfl(corr, qloc);
                    o0[r] *= cr; o1[r] *= cr;
                }
            }
#pragma unroll
            for (int r = 0; r < 16; ++r) s[r] = exp2fast(s[r] - m_run);

            // ---- l: tree sum + cross-half combine ----
            {
                float p0 = 0.f, p1 = 0.f, p2 = 0.f, p3 = 0.f;
#pragma unroll
                for (int r = 0; r < 16; r += 4) {
                    p0 += s[r]; p1 += s[r + 1]; p2 += s[r + 2]; p3 += s[r + 3];
                }
                float rs = (p0 + p1) + (p2 + p3);
                rs += __shfl_xor(rs, 32);
                l_run += rs;
            }

            // ---- PV: fused cvt+permlane+MFMA per 16-key slice ----
            __builtin_amdgcn_s_setprio(1);
#pragma unroll
            for (int ksl = 0; ksl < 2; ++ksl) {
                const int off = ksl * 8;
                unsigned x0 = cvtpk(s[off],     s[off + 1]);
                unsigned x1 = cvtpk(s[off + 2], s[off + 3]);
                unsigned y0 = cvtpk(s[off + 4], s[off + 5]);
                unsigned y1 = cvtpk(s[off + 6], s[off + 7]);
                pswap(x0, y0);   // x0' = frag word0, y0' = frag word2
                pswap(x1, y1);   // x1' = frag word1, y1' = frag word3
                union { unsigned u[4]; short8_t v; } pa;
                pa.u[0] = x0; pa.u[1] = x1; pa.u[2] = y0; pa.u[3] = y1;
                const int ksg = 2 * h + ksl;
                short8_t vf0 = ldf(bV, ql,      2 * ksg + hi);
                short8_t vf1 = ldf(bV, 32 + ql, 2 * ksg + hi);
                o0 = __builtin_amdgcn_mfma_f32_32x32x16_bf16(pa.v, vf0, o0, 0, 0, 0);
                o1 = __builtin_amdgcn_mfma_f32_32x32x16_bf16(pa.v, vf1, o1, 0, 0, 0);
            }
            __builtin_amdgcn_s_setprio(0);
        }
        __syncthreads();   // drains gload_lds (next tile) + guards buffer reuse
    }

    // ---- epilogue: 1/l redistribution via shfl, store fp32 ----
    const float inv = 1.0f / l_run;
#pragma unroll
    for (int r = 0; r < 16; ++r) {
        const int qloc = (r & 3) + 8 * (r >> 2) + 4 * hi;
        const float iv = __shfl(inv, qloc);
        float* orow = Op + ((size_t)bh * Sn + q0 + w * 32 + qloc) * 64;
        orow[ql] = o0[r] * iv;
        orow[32 + ql] = o1[r] * iv;
    }
}

// ================= fallback (round-2 kernel, proven) =================
__global__ __launch_bounds__(512, 4) void sdpa_v2(
    const float* __restrict__ Qp, const float* __restrict__ Kp,
    const float* __restrict__ Vp, const void* __restrict__ Mp,
    const unsigned long long* __restrict__ PM, float* __restrict__ Op)
{
    __shared__ unsigned short lds_k[64 * 64];
    __shared__ unsigned short lds_vt[64 * 64];
    __shared__ unsigned short lds_p[8][16 * 64];

    const int t = threadIdx.x;
    const int wave = t >> 6;
    const int lane = t & 63;
    const int g = lane >> 4;
    const int c = lane & 15;

    const int gid = blockIdx.x;
    const int lin = (gid & 7) * 128 + (gid >> 3);
    const int bh = lin >> 4;
    const int qb = lin & 15;
    const int b = bh >> 4;
    const int q0 = qb * 128;

    bool m_i32 = true;
    if (!PM) {
        unsigned accv = 0;
        const unsigned* mw = (const unsigned*)Mp;
#pragma unroll
        for (int i = 0; i < 32; ++i) accv |= (mw[i] & 0xFFFFFF00u);
        m_i32 = (accv == 0u);
    }
    const int* mi32 = (const int*)Mp;
    const unsigned char* mu8 = (const unsigned char*)Mp;

    short8_t qf[2];
    {
        const float qscale = 0.125f * 1.44269504088896340736f;
        const float* qsrc = Qp + ((size_t)bh * Sn + q0 + wave * 16 + c) * Dn + g * 8;
#pragma unroll
        for (int h2 = 0; h2 < 2; ++h2) {
            f32x4 f0 = *(const f32x4*)(qsrc + h2 * 32);
            f32x4 f1 = *(const f32x4*)(qsrc + h2 * 32 + 4);
            short8_t v;
            v[0]=(short)f2bf(f0[0]*qscale); v[1]=(short)f2bf(f0[1]*qscale);
            v[2]=(short)f2bf(f0[2]*qscale); v[3]=(short)f2bf(f0[3]*qscale);
            v[4]=(short)f2bf(f1[0]*qscale); v[5]=(short)f2bf(f1[1]*qscale);
            v[6]=(short)f2bf(f1[2]*qscale); v[7]=(short)f2bf(f1[3]*qscale);
            qf[h2] = v;
        }
    }

    f32x4 o[4];
#pragma unroll
    for (int i = 0; i < 4; ++i) o[i] = (f32x4){0.f, 0.f, 0.f, 0.f};
    float m_run[4] = {-INFINITY, -INFINITY, -INFINITY, -INFINITY};
    float l_run[4] = {0.f, 0.f, 0.f, 0.f};

    const float* kbase = Kp + (size_t)bh * Sn * Dn;
    const float* vbase = Vp + (size_t)bh * Sn * Dn;
    const size_t mrow0 = (size_t)b * Sn + q0 + wave * 16 + g * 4;

    for (int kt = 0; kt < NKT; ++kt) {
        const int k0 = kt * 64;
        {
            const int key = t >> 3;
            const int d0 = (t & 7) * 8;
            const float* src = kbase + (size_t)(k0 + key) * Dn + d0;
            f32x4 f0 = *(const f32x4*)src;
            f32x4 f1 = *(const f32x4*)(src + 4);
            short8_t hv;
            hv[0]=(short)f2bf(f0[0]); hv[1]=(short)f2bf(f0[1]);
            hv[2]=(short)f2bf(f0[2]); hv[3]=(short)f2bf(f0[3]);
            hv[4]=(short)f2bf(f1[0]); hv[5]=(short)f2bf(f1[1]);
            hv[6]=(short)f2bf(f1[2]); hv[7]=(short)f2bf(f1[3]);
            *(short8_t*)&lds_k[key * 64 + (d0 ^ (sw8(key) << 3))] = hv;
        }
        {
            const int vv = t & 63;
            const int kq = (t >> 6) * 8;
            short8_t hv;
#pragma unroll
            for (int j = 0; j < 8; ++j)
                hv[j] = (short)f2bf(vbase[(size_t)(k0 + kq + j) * Dn + vv]);
            *(short8_t*)&lds_vt[vv * 64 + (kq ^ (sw8(vv) << 3))] = hv;
        }
        __syncthreads();

        f32x4 s[4];
#pragma unroll
        for (int e = 0; e < 4; ++e) s[e] = (f32x4){0.f, 0.f, 0.f, 0.f};
        __builtin_amdgcn_s_setprio(1);
#pragma unroll
        for (int e = 0; e < 4; ++e) {
            const int ke = e * 16 + c;
            const int swk = sw8(ke) << 3;
            short8_t kf0 = *(const short8_t*)&lds_k[ke * 64 + ((g * 8) ^ swk)];
            short8_t kf1 = *(const short8_t*)&lds_k[ke * 64 + ((32 + g * 8) ^ swk)];
            s[e] = __builtin_amdgcn_mfma_f32_16x16x32_bf16(qf[0], kf0, s[e], 0, 0, 0);
            s[e] = __builtin_amdgcn_mfma_f32_16x16x32_bf16(qf[1], kf1, s[e], 0, 0, 0);
        }
        __builtin_amdgcn_s_setprio(0);

        unsigned long long bits[4];
        if (PM) {
#pragma unroll
            for (int r = 0; r < 4; ++r) bits[r] = PM[(mrow0 + r) * MW + kt];
        } else {
#pragma unroll
            for (int r = 0; r < 4; ++r) {
                const size_t mi = (mrow0 + r) * Sn + k0 + c;
                unsigned long long bbv = 0;
#pragma unroll
                for (int e = 0; e < 4; ++e) {
                    int mm = m_i32 ? mi32[mi + 16 * e] : (int)mu8[mi + 16 * e];
                    bbv |= (unsigned long long)(mm != 0) << (c + 16 * e);
                }
                bits[r] = bbv;
            }
        }

        float p[4][4], mx[4];
#pragma unroll
        for (int r = 0; r < 4; ++r) {
            const unsigned lo = (unsigned)bits[r];
            const unsigned hh = (unsigned)(bits[r] >> 32);
            const unsigned t0 = lo >> c;
            const unsigned t1 = hh >> c;
            float v0 = (t0 & 1u)       ? -1e9f : s[0][r];
            float v1 = (t0 & 0x10000u) ? -1e9f : s[1][r];
            float v2 = (t1 & 1u)       ? -1e9f : s[2][r];
            float v3 = (t1 & 0x10000u) ? -1e9f : s[3][r];
            p[0][r] = v0; p[1][r] = v1; p[2][r] = v2; p[3][r] = v3;
            mx[r] = fmaxf(fmaxf(v0, v1), fmaxf(v2, v3));
        }
#pragma unroll
        for (int sh = 1; sh < 16; sh <<= 1) {
#pragma unroll
            for (int r = 0; r < 4; ++r) mx[r] = fmaxf(mx[r], __shfl_xor(mx[r], sh));
        }
        float need = mx[0] - m_run[0];
        need = fmaxf(need, mx[1] - m_run[1]);
        need = fmaxf(need, mx[2] - m_run[2]);
        need = fmaxf(need, mx[3] - m_run[3]);
        if (!__all(need <= 8.0f)) {
#pragma unroll
            for (int r = 0; r < 4; ++r) {
                const float mn = fmaxf(m_run[r], mx[r]);
                const float corr = exp2fast(m_run[r] - mn);
                m_run[r] = mn;
                l_run[r] *= corr;
#pragma unroll
                for (int cg = 0; cg < 4; ++cg) o[cg][r] *= corr;
            }
        }
        float rsv[4];
#pragma unroll
        for (int r = 0; r < 4; ++r) {
            p[0][r] = exp2fast(p[0][r] - m_run[r]);
            p[1][r] = exp2fast(p[1][r] - m_run[r]);
            p[2][r] = exp2fast(p[2][r] - m_run[r]);
            p[3][r] = exp2fast(p[3][r] - m_run[r]);
            rsv[r] = (p[0][r] + p[1][r]) + (p[2][r] + p[3][r]);
        }
#pragma unroll
        for (int sh = 1; sh < 16; sh <<= 1) {
#pragma unroll
            for (int r = 0; r < 4; ++r) rsv[r] += __shfl_xor(rsv[r], sh);
        }
#pragma unroll
        for (int r = 0; r < 4; ++r) l_run[r] += rsv[r];

        unsigned short* pw = lds_p[wave];
#pragma unroll
        for (int r = 0; r < 4; ++r) {
            const int row = g * 4 + r;
            const int swp = sw8(row) << 3;
            pw[row * 64 + ((c)      ^ swp)] = f2bf(p[0][r]);
            pw[row * 64 + ((c + 16) ^ swp)] = f2bf(p[1][r]);
            pw[row * 64 + ((c + 32) ^ swp)] = f2bf(p[2][r]);
            pw[row * 64 + ((c + 48) ^ swp)] = f2bf(p[3][r]);
        }
        const int swc = sw8(c) << 3;
        const short8_t pf0 = *(const short8_t*)&pw[c * 64 + ((g * 8) ^ swc)];
        const short8_t pf1 = *(const short8_t*)&pw[c * 64 + ((32 + g * 8) ^ swc)];
        __builtin_amdgcn_s_setprio(1);
#pragma unroll
        for (int cg = 0; cg < 4; ++cg) {
            const int vv = cg * 16 + c;
            const int swv = sw8(vv) << 3;
            const short8_t vf0 = *(const short8_t*)&lds_vt[vv * 64 + ((g * 8) ^ swv)];
            const short8_t vf1 = *(const short8_t*)&lds_vt[vv * 64 + ((32 + g * 8) ^ swv)];
            o[cg] = __builtin_amdgcn_mfma_f32_16x16x32_bf16(pf0, vf0, o[cg], 0, 0, 0);
            o[cg] = __builtin_amdgcn_mfma_f32_16x16x32_bf16(pf1, vf1, o[cg], 0, 0, 0);
        }
        __builtin_amdgcn_s_setprio(0);
        __syncthreads();
    }

#pragma unroll
    for (int r = 0; r < 4; ++r) {
        const float inv = 1.0f / l_run[r];
        float* orow = Op + ((size_t)bh * Sn + q0 + wave * 16 + g * 4 + r) * Dn + c;
#pragma unroll
        for (int cg = 0; cg < 4; ++cg) orow[cg * 16] = o[cg][r] * inv;
    }
}

extern "C" void kernel_launch(void* const* d_in, const int* in_sizes, int n_in,
                              void* d_out, int out_size, void* d_ws, size_t ws_size,
                              hipStream_t stream) {
    (void)in_sizes; (void)n_in; (void)out_size;
    const float* Q = (const float*)d_in[0];
    const float* K = (const float*)d_in[1];
    const float* V = (const float*)d_in[2];
    const void*  M = d_in[3];
    float* O = (float*)d_out;

    const size_t pmB = (size_t)Bn * Sn * MW * 8;            // 2 MB packed mask
    const size_t kvB = (size_t)Bn * Hn * Sn * Dn * 2;       // 16.78 MB each

    if (ws_size >= pmB + 2 * kvB) {
        unsigned long long* PM = (unsigned long long*)d_ws;
        unsigned short* Kb = (unsigned short*)((char*)d_ws + pmB);
        unsigned short* Vt = (unsigned short*)((char*)d_ws + pmB + kvB);
        convKV<<<dim3(Bn * Hn, NKT), 256, 0, stream>>>(K, V, M, Kb, Vt, PM);
        sdpa_v3<<<dim3(1024), dim3(256), 0, stream>>>(Q, Kb, Vt, PM, O);
    } else {
        unsigned long long* PM = nullptr;
        if (ws_size >= pmB) {
            PM = (unsigned long long*)d_ws;
            pack_mask<<<1024, 256, 0, stream>>>(M, PM);
        }
        sdpa_v2<<<dim3(1024), dim3(512), 0, stream>>>(Q, K, V, M, PM, O);
    }
}

// Round 12
// 140.077 us; speedup vs baseline: 1.0362x; 1.0215x over previous
//
#include <hip/hip_runtime.h>
#include <hip/hip_bf16.h>
#include <math.h>

typedef __attribute__((ext_vector_type(4)))  float f32x4;
typedef __attribute__((ext_vector_type(16))) float f32x16;
typedef __attribute__((ext_vector_type(8)))  short short8_t;
typedef __attribute__((ext_vector_type(4)))  short short4_t;

constexpr int Bn = 4, Hn = 16, Sn = 2048, Dn = 64;
constexpr int MW  = Sn / 64;   // packed-mask u64 words per row = 32
constexpr int NKT = Sn / 64;   // 64-key tiles = 32

__device__ __forceinline__ unsigned short f2bf(float f) {
    union { float f; unsigned u; } x; x.f = f;
    unsigned r = x.u + 0x7fffu + ((x.u >> 16) & 1u);  // RTNE
    return (unsigned short)(r >> 16);
}
__device__ __forceinline__ int sw8(int row) { return (row ^ (row >> 3)) & 7; }
__device__ __forceinline__ float exp2fast(float x) {
#if __has_builtin(__builtin_amdgcn_exp2f)
    return __builtin_amdgcn_exp2f(x);
#else
    float r; asm("v_exp_f32 %0, %1" : "=v"(r) : "v"(x)); return r;
#endif
}
__device__ __forceinline__ float max3f(float a, float b, float c) {
    return fmaxf(fmaxf(a, b), c);   // fuses to v_max3_f32
}
__device__ __forceinline__ f32x16 zero16() {
    f32x16 z;
#pragma unroll
    for (int i = 0; i < 16; ++i) z[i] = 0.f;
    return z;
}
__device__ __forceinline__ unsigned cvtpk(float lo, float hi_) {
    __hip_bfloat162 h2 = __float22bfloat162_rn(make_float2(lo, hi_));
    union { __hip_bfloat162 h; unsigned u; } u; u.h = h2;
    return u.u;
}
// v_permlane32_swap_b32: X' = [X_lo, Y_lo], Y' = [X_hi, Y_hi]
__device__ __forceinline__ void pswap(unsigned &x, unsigned &y) {
    asm("v_permlane32_swap_b32 %0, %1" : "+v"(x), "+v"(y));
}

// ================= prepass kernels =================
// standalone pack_mask kept for the no-workspace fallback path
__global__ __launch_bounds__(256) void pack_mask(const void* __restrict__ Mp,
                                                 unsigned long long* __restrict__ PM) {
    unsigned accv = 0;
    {
        const unsigned* mw = (const unsigned*)Mp;
#pragma unroll
        for (int i = 0; i < 8; ++i) accv |= (mw[i] & 0xFFFFFF00u);
    }
    const bool i32 = (accv == 0u);
    const int lane = threadIdx.x & 63;
    const int wv = (int)((blockIdx.x * 256 + threadIdx.x) >> 6);   // 4096 waves
    const int w0 = wv * (Bn * Sn * MW / 4096);                     // 64 words/wave
    const int* mi32 = (const int*)Mp;
    const unsigned char* mu8 = (const unsigned char*)Mp;
    for (int j = 0; j < 64; j += 4) {
        int m0, m1, m2, m3;
        if (i32) {
            m0 = mi32[(size_t)(w0 + j) * 64 + lane];
            m1 = mi32[(size_t)(w0 + j + 1) * 64 + lane];
            m2 = mi32[(size_t)(w0 + j + 2) * 64 + lane];
            m3 = mi32[(size_t)(w0 + j + 3) * 64 + lane];
        } else {
            m0 = mu8[(size_t)(w0 + j) * 64 + lane];
            m1 = mu8[(size_t)(w0 + j + 1) * 64 + lane];
            m2 = mu8[(size_t)(w0 + j + 2) * 64 + lane];
            m3 = mu8[(size_t)(w0 + j + 3) * 64 + lane];
        }
        unsigned long long b0 = __ballot(m0 != 0);
        unsigned long long b1 = __ballot(m1 != 0);
        unsigned long long b2 = __ballot(m2 != 0);
        unsigned long long b3 = __ballot(m3 != 0);
        if (lane == 0) {
            PM[w0 + j] = b0; PM[w0 + j + 1] = b1;
            PM[w0 + j + 2] = b2; PM[w0 + j + 3] = b3;
        }
    }
}

// fused prepass: K->bf16 (linear) + V->bf16 transposed + this block's 128 mask
// words packed to bits. One block per (bh, kt).
__global__ __launch_bounds__(256) void convKV(const float* __restrict__ K,
                                              const float* __restrict__ V,
                                              const void* __restrict__ Mp,
                                              unsigned short* __restrict__ Kb,
                                              unsigned short* __restrict__ Vt,
                                              unsigned long long* __restrict__ PM) {
    __shared__ unsigned short tile[64 * 72];
    const int bh = blockIdx.x, kt = blockIdx.y, t = threadIdx.x;

    // ---- K: 64 rows x 64 d, straight bf16 convert ----
    {
        const float* ksrc = K + ((size_t)bh * Sn + kt * 64) * 64;
        unsigned short* kdst = Kb + ((size_t)bh * Sn + kt * 64) * 64;
#pragma unroll
        for (int j = 0; j < 2; ++j) {
            const int idx = j * 256 + t;       // 512 chunks of 8 floats
            f32x4 a = *(const f32x4*)(ksrc + idx * 8);
            f32x4 b = *(const f32x4*)(ksrc + idx * 8 + 4);
            short8_t h;
            h[0]=(short)f2bf(a[0]); h[1]=(short)f2bf(a[1]); h[2]=(short)f2bf(a[2]); h[3]=(short)f2bf(a[3]);
            h[4]=(short)f2bf(b[0]); h[5]=(short)f2bf(b[1]); h[6]=(short)f2bf(b[2]); h[7]=(short)f2bf(b[3]);
            *(short8_t*)(kdst + idx * 8) = h;
        }
    }

    // ---- mask pack: 128 u64 words for this block (32 per wave) ----
    {
        unsigned accv = 0;
        const unsigned* mw = (const unsigned*)Mp;
#pragma unroll
        for (int i = 0; i < 8; ++i) accv |= (mw[i] & 0xFFFFFF00u);
        const bool i32 = (accv == 0u);
        const int wv = t >> 6, lane = t & 63;
        const int base = (bh * NKT + kt) * 128 + wv * 32;
        const int* mi32 = (const int*)Mp;
        const unsigned char* mu8 = (const unsigned char*)Mp;
#pragma unroll 4
        for (int j = 0; j < 32; ++j) {
            int m = i32 ? mi32[(size_t)(base + j) * 64 + lane]
                        : (int)mu8[(size_t)(base + j) * 64 + lane];
            unsigned long long bal = __ballot(m != 0);
            if (lane == 0) PM[base + j] = bal;
        }
    }

    // ---- V: transpose via LDS -> Vt[bh][v][k] ----
    {
        const int k = t >> 2, vq = (t & 3) * 16;
        const float* src = V + ((size_t)bh * Sn + kt * 64 + k) * 64 + vq;
#pragma unroll
        for (int j = 0; j < 4; ++j) {
            f32x4 f = *(const f32x4*)(src + j * 4);
            short4_t h;
            h[0]=(short)f2bf(f[0]); h[1]=(short)f2bf(f[1]); h[2]=(short)f2bf(f[2]); h[3]=(short)f2bf(f[3]);
            *(short4_t*)&tile[k * 72 + vq + j * 4] = h;
        }
        __syncthreads();
#pragma unroll
        for (int j = 0; j < 2; ++j) {
            const int v = (t >> 3) + 32 * j;
            const int oct = t & 7;
            short8_t h;
#pragma unroll
            for (int i2 = 0; i2 < 8; ++i2) h[i2] = (short)tile[(oct * 8 + i2) * 72 + v];
            *(short8_t*)(Vt + ((size_t)bh * 64 + v) * Sn + kt * 64 + oct * 8) = h;
        }
    }
}

// ====== main kernel (v9): QTILE=256 (8 waves, 512 blocks = 2/CU), inner loop
//        identical to the proven round-9 kernel; Q frags loaded direct ======
__global__ __launch_bounds__(512, 4) void sdpa_v3(
    const float* __restrict__ Qp, const unsigned short* __restrict__ Kb,
    const unsigned short* __restrict__ Vt, const unsigned long long* __restrict__ PM,
    float* __restrict__ Op)
{
    __shared__ __align__(16) char smem[32768];
    unsigned short* smK = (unsigned short*)smem;            // [2][4096]
    unsigned short* smV = (unsigned short*)(smem + 16384);  // [2][4096]

    const int t = threadIdx.x;
    const int w = t >> 6;       // 0..7
    const int l = t & 63;
    const int ql = l & 31;
    const int hi = l >> 5;

    // XCD-aware remap (512 blocks = 8 XCD * 64; 512%8==0 -> bijective)
    const int gid = blockIdx.x;
    const int lin = (gid & 7) * 64 + (gid >> 3);
    const int bh = lin >> 3;    // 8 q-blocks per head
    const int qb = lin & 7;
    const int b = bh >> 4;
    const int q0 = qb * 256;

    const unsigned short* KbB = Kb + (size_t)bh * Sn * 64;
    const unsigned short* VtB = Vt + (size_t)bh * 64 * Sn;

    // ---- staging: global_load_lds 16B; 512 threads x 16B = one 8KB tile each ----
    auto stage = [&](int kt, int buf) {
        const int row = t >> 3, oct = t & 7;   // 64 rows x 8 octs
        {
            const unsigned short* g = KbB + ((size_t)(kt * 64 + row)) * 64 + (oct ^ sw8(row)) * 8;
            __builtin_amdgcn_global_load_lds((const __attribute__((address_space(1))) unsigned int*)g,
                (__attribute__((address_space(3))) unsigned int*)(smK + buf * 4096 + t * 8), 16, 0, 0);
        }
        {
            const unsigned short* g = VtB + (size_t)row * Sn + kt * 64 + (oct ^ sw8(row)) * 8;
            __builtin_amdgcn_global_load_lds((const __attribute__((address_space(1))) unsigned int*)g,
                (__attribute__((address_space(3))) unsigned int*)(smV + buf * 4096 + t * 8), 16, 0, 0);
        }
    };
    auto ldf = [&](const unsigned short* base, int row, int olog) -> short8_t {
        return *(const short8_t*)(base + row * 64 + (olog ^ sw8(row)) * 8);
    };

    // kick off tile 0 before the (one-time) Q fragment load
    stage(0, 0);

    // ---- Q fragments direct from global (bf16, scaled); one-time, L3-warm ----
    short8_t qf[4];
    {
        const float qscale = 0.125f * 1.44269504088896340736f;  // 1/sqrt(64) * log2(e)
        const float* qsrc = Qp + ((size_t)bh * Sn + q0 + w * 32 + ql) * Dn + hi * 8;
#pragma unroll
        for (int tt = 0; tt < 4; ++tt) {
            f32x4 f0 = *(const f32x4*)(qsrc + tt * 16);
            f32x4 f1 = *(const f32x4*)(qsrc + tt * 16 + 4);
            short8_t v;
            v[0]=(short)f2bf(f0[0]*qscale); v[1]=(short)f2bf(f0[1]*qscale);
            v[2]=(short)f2bf(f0[2]*qscale); v[3]=(short)f2bf(f0[3]*qscale);
            v[4]=(short)f2bf(f1[0]*qscale); v[5]=(short)f2bf(f1[1]*qscale);
            v[6]=(short)f2bf(f1[2]*qscale); v[7]=(short)f2bf(f1[3]*qscale);
            qf[tt] = v;
        }
    }

    f32x16 o0 = zero16(), o1 = zero16();
    float m_run = -INFINITY, l_run = 0.f;
    const int qrow = q0 + w * 32 + ql;
    const unsigned long long* pmrow = PM + ((size_t)b * Sn + qrow) * MW;

    __syncthreads();   // drains stage(0)'s gload_lds (compiler emits vmcnt(0))

    for (int kt = 0; kt < NKT; ++kt) {
        const int cur = kt & 1;
        if (kt + 1 < NKT) stage(kt + 1, cur ^ 1);
        const unsigned long long bits = pmrow[kt];
        const unsigned short* bK = smK + cur * 4096;
        const unsigned short* bV = smV + cur * 4096;

#pragma unroll
        for (int h = 0; h < 2; ++h) {
            // ---- QK^T (swapped): 32 keys of this half, lane q = ql ----
            f32x16 s = zero16();
            __builtin_amdgcn_s_setprio(1);
#pragma unroll
            for (int tt = 0; tt < 4; ++tt) {
                short8_t a0 = ldf(bK, 32 * h + ql, 2 * tt + hi);
                s = __builtin_amdgcn_mfma_f32_32x32x16_bf16(a0, qf[tt], s, 0, 0, 0);
            }
            __builtin_amdgcn_s_setprio(0);

            // ---- mask (reg r: key = 32h + (r&3) + 8*(r>>2) + 4*hi) ----
            const unsigned w32 = (unsigned)(bits >> (32 * h)) >> (hi * 4);
#pragma unroll
            for (int r = 0; r < 16; ++r) {
                const int bp = 8 * (r >> 2) + (r & 3);
                s[r] = ((w32 >> bp) & 1u) ? -1e9f : s[r];
            }

            // ---- online max (v_max3 chain), lane-local q-row ----
            float mx = fmaxf(s[0], s[1]);
#pragma unroll
            for (int r = 2; r < 16; r += 2) mx = max3f(mx, s[r], s[r + 1]);
            mx = fmaxf(mx, __shfl_xor(mx, 32));

            if (!__all(mx - m_run <= 8.0f)) {   // defer-max (THR=8, log2 domain)
                const float mn = fmaxf(m_run, mx);
                const float corr = exp2fast(m_run - mn);
                m_run = mn;
                l_run *= corr;
#pragma unroll
                for (int r = 0; r < 16; ++r) {
                    const int qloc = (r & 3) + 8 * (r >> 2) + 4 * hi;
                    const float cr = __shfl(corr, qloc);
                    o0[r] *= cr; o1[r] *= cr;
                }
            }
#pragma unroll
            for (int r = 0; r < 16; ++r) s[r] = exp2fast(s[r] - m_run);

            // ---- l: tree sum + cross-half combine ----
            {
                float p0 = 0.f, p1 = 0.f, p2 = 0.f, p3 = 0.f;
#pragma unroll
                for (int r = 0; r < 16; r += 4) {
                    p0 += s[r]; p1 += s[r + 1]; p2 += s[r + 2]; p3 += s[r + 3];
                }
                float rs = (p0 + p1) + (p2 + p3);
                rs += __shfl_xor(rs, 32);
                l_run += rs;
            }

            // ---- PV: fused cvt+permlane+MFMA per 16-key slice ----
            __builtin_amdgcn_s_setprio(1);
#pragma unroll
            for (int ksl = 0; ksl < 2; ++ksl) {
                const int off = ksl * 8;
                unsigned x0 = cvtpk(s[off],     s[off + 1]);
                unsigned x1 = cvtpk(s[off + 2], s[off + 3]);
                unsigned y0 = cvtpk(s[off + 4], s[off + 5]);
                unsigned y1 = cvtpk(s[off + 6], s[off + 7]);
                pswap(x0, y0);   // x0' = frag word0, y0' = frag word2
                pswap(x1, y1);   // x1' = frag word1, y1' = frag word3
                union { unsigned u[4]; short8_t v; } pa;
                pa.u[0] = x0; pa.u[1] = x1; pa.u[2] = y0; pa.u[3] = y1;
                const int ksg = 2 * h + ksl;
                short8_t vf0 = ldf(bV, ql,      2 * ksg + hi);
                short8_t vf1 = ldf(bV, 32 + ql, 2 * ksg + hi);
                o0 = __builtin_amdgcn_mfma_f32_32x32x16_bf16(pa.v, vf0, o0, 0, 0, 0);
                o1 = __builtin_amdgcn_mfma_f32_32x32x16_bf16(pa.v, vf1, o1, 0, 0, 0);
            }
            __builtin_amdgcn_s_setprio(0);
        }
        __syncthreads();   // drains gload_lds (next tile) + guards buffer reuse
    }

    // ---- epilogue: 1/l redistribution via shfl, store fp32 ----
    const float inv = 1.0f / l_run;
#pragma unroll
    for (int r = 0; r < 16; ++r) {
        const int qloc = (r & 3) + 8 * (r >> 2) + 4 * hi;
        const float iv = __shfl(inv, qloc);
        float* orow = Op + ((size_t)bh * Sn + q0 + w * 32 + qloc) * 64;
        orow[ql] = o0[r] * iv;
        orow[32 + ql] = o1[r] * iv;
    }
}

// ================= fallback (round-2 kernel, proven) =================
__global__ __launch_bounds__(512, 4) void sdpa_v2(
    const float* __restrict__ Qp, const float* __restrict__ Kp,
    const float* __restrict__ Vp, const void* __restrict__ Mp,
    const unsigned long long* __restrict__ PM, float* __restrict__ Op)
{
    __shared__ unsigned short lds_k[64 * 64];
    __shared__ unsigned short lds_vt[64 * 64];
    __shared__ unsigned short lds_p[8][16 * 64];

    const int t = threadIdx.x;
    const int wave = t >> 6;
    const int lane = t & 63;
    const int g = lane >> 4;
    const int c = lane & 15;

    const int gid = blockIdx.x;
    const int lin = (gid & 7) * 128 + (gid >> 3);
    const int bh = lin >> 4;
    const int qb = lin & 15;
    const int b = bh >> 4;
    const int q0 = qb * 128;

    bool m_i32 = true;
    if (!PM) {
        unsigned accv = 0;
        const unsigned* mw = (const unsigned*)Mp;
#pragma unroll
        for (int i = 0; i < 32; ++i) accv |= (mw[i] & 0xFFFFFF00u);
        m_i32 = (accv == 0u);
    }
    const int* mi32 = (const int*)Mp;
    const unsigned char* mu8 = (const unsigned char*)Mp;

    short8_t qf[2];
    {
        const float qscale = 0.125f * 1.44269504088896340736f;
        const float* qsrc = Qp + ((size_t)bh * Sn + q0 + wave * 16 + c) * Dn + g * 8;
#pragma unroll
        for (int h2 = 0; h2 < 2; ++h2) {
            f32x4 f0 = *(const f32x4*)(qsrc + h2 * 32);
            f32x4 f1 = *(const f32x4*)(qsrc + h2 * 32 + 4);
            short8_t v;
            v[0]=(short)f2bf(f0[0]*qscale); v[1]=(short)f2bf(f0[1]*qscale);
            v[2]=(short)f2bf(f0[2]*qscale); v[3]=(short)f2bf(f0[3]*qscale);
            v[4]=(short)f2bf(f1[0]*qscale); v[5]=(short)f2bf(f1[1]*qscale);
            v[6]=(short)f2bf(f1[2]*qscale); v[7]=(short)f2bf(f1[3]*qscale);
            qf[h2] = v;
        }
    }

    f32x4 o[4];
#pragma unroll
    for (int i = 0; i < 4; ++i) o[i] = (f32x4){0.f, 0.f, 0.f, 0.f};
    float m_run[4] = {-INFINITY, -INFINITY, -INFINITY, -INFINITY};
    float l_run[4] = {0.f, 0.f, 0.f, 0.f};

    const float* kbase = Kp + (size_t)bh * Sn * Dn;
    const float* vbase = Vp + (size_t)bh * Sn * Dn;
    const size_t mrow0 = (size_t)b * Sn + q0 + wave * 16 + g * 4;

    for (int kt = 0; kt < NKT; ++kt) {
        const int k0 = kt * 64;
        {
            const int key = t >> 3;
            const int d0 = (t & 7) * 8;
            const float* src = kbase + (size_t)(k0 + key) * Dn + d0;
            f32x4 f0 = *(const f32x4*)src;
            f32x4 f1 = *(const f32x4*)(src + 4);
            short8_t hv;
            hv[0]=(short)f2bf(f0[0]); hv[1]=(short)f2bf(f0[1]);
            hv[2]=(short)f2bf(f0[2]); hv[3]=(short)f2bf(f0[3]);
            hv[4]=(short)f2bf(f1[0]); hv[5]=(short)f2bf(f1[1]);
            hv[6]=(short)f2bf(f1[2]); hv[7]=(short)f2bf(f1[3]);
            *(short8_t*)&lds_k[key * 64 + (d0 ^ (sw8(key) << 3))] = hv;
        }
        {
            const int vv = t & 63;
            const int kq = (t >> 6) * 8;
            short8_t hv;
#pragma unroll
            for (int j = 0; j < 8; ++j)
                hv[j] = (short)f2bf(vbase[(size_t)(k0 + kq + j) * Dn + vv]);
            *(short8_t*)&lds_vt[vv * 64 + (kq ^ (sw8(vv) << 3))] = hv;
        }
        __syncthreads();

        f32x4 s[4];
#pragma unroll
        for (int e = 0; e < 4; ++e) s[e] = (f32x4){0.f, 0.f, 0.f, 0.f};
        __builtin_amdgcn_s_setprio(1);
#pragma unroll
        for (int e = 0; e < 4; ++e) {
            const int ke = e * 16 + c;
            const int swk = sw8(ke) << 3;
            short8_t kf0 = *(const short8_t*)&lds_k[ke * 64 + ((g * 8) ^ swk)];
            short8_t kf1 = *(const short8_t*)&lds_k[ke * 64 + ((32 + g * 8) ^ swk)];
            s[e] = __builtin_amdgcn_mfma_f32_16x16x32_bf16(qf[0], kf0, s[e], 0, 0, 0);
            s[e] = __builtin_amdgcn_mfma_f32_16x16x32_bf16(qf[1], kf1, s[e], 0, 0, 0);
        }
        __builtin_amdgcn_s_setprio(0);

        unsigned long long bits[4];
        if (PM) {
#pragma unroll
            for (int r = 0; r < 4; ++r) bits[r] = PM[(mrow0 + r) * MW + kt];
        } else {
#pragma unroll
            for (int r = 0; r < 4; ++r) {
                const size_t mi = (mrow0 + r) * Sn + k0 + c;
                unsigned long long bbv = 0;
#pragma unroll
                for (int e = 0; e < 4; ++e) {
                    int mm = m_i32 ? mi32[mi + 16 * e] : (int)mu8[mi + 16 * e];
                    bbv |= (unsigned long long)(mm != 0) << (c + 16 * e);
                }
                bits[r] = bbv;
            }
        }

        float p[4][4], mx[4];
#pragma unroll
        for (int r = 0; r < 4; ++r) {
            const unsigned lo = (unsigned)bits[r];
            const unsigned hh = (unsigned)(bits[r] >> 32);
            const unsigned t0 = lo >> c;
            const unsigned t1 = hh >> c;
            float v0 = (t0 & 1u)       ? -1e9f : s[0][r];
            float v1 = (t0 & 0x10000u) ? -1e9f : s[1][r];
            float v2 = (t1 & 1u)       ? -1e9f : s[2][r];
            float v3 = (t1 & 0x10000u) ? -1e9f : s[3][r];
            p[0][r] = v0; p[1][r] = v1; p[2][r] = v2; p[3][r] = v3;
            mx[r] = fmaxf(fmaxf(v0, v1), fmaxf(v2, v3));
        }
#pragma unroll
        for (int sh = 1; sh < 16; sh <<= 1) {
#pragma unroll
            for (int r = 0; r < 4; ++r) mx[r] = fmaxf(mx[r], __shfl_xor(mx[r], sh));
        }
        float need = mx[0] - m_run[0];
        need = fmaxf(need, mx[1] - m_run[1]);
        need = fmaxf(need, mx[2] - m_run[2]);
        need = fmaxf(need, mx[3] - m_run[3]);
        if (!__all(need <= 8.0f)) {
#pragma unroll
            for (int r = 0; r < 4; ++r) {
                const float mn = fmaxf(m_run[r], mx[r]);
                const float corr = exp2fast(m_run[r] - mn);
                m_run[r] = mn;
                l_run[r] *= corr;
#pragma unroll
                for (int cg = 0; cg < 4; ++cg) o[cg][r] *= corr;
            }
        }
        float rsv[4];
#pragma unroll
        for (int r = 0; r < 4; ++r) {
            p[0][r] = exp2fast(p[0][r] - m_run[r]);
            p[1][r] = exp2fast(p[1][r] - m_run[r]);
            p[2][r] = exp2fast(p[2][r] - m_run[r]);
            p[3][r] = exp2fast(p[3][r] - m_run[r]);
            rsv[r] = (p[0][r] + p[1][r]) + (p[2][r] + p[3][r]);
        }
#pragma unroll
        for (int sh = 1; sh < 16; sh <<= 1) {
#pragma unroll
            for (int r = 0; r < 4; ++r) rsv[r] += __shfl_xor(rsv[r], sh);
        }
#pragma unroll
        for (int r = 0; r < 4; ++r) l_run[r] += rsv[r];

        unsigned short* pw = lds_p[wave];
#pragma unroll
        for (int r = 0; r < 4; ++r) {
            const int row = g * 4 + r;
            const int swp = sw8(row) << 3;
            pw[row * 64 + ((c)      ^ swp)] = f2bf(p[0][r]);
            pw[row * 64 + ((c + 16) ^ swp)] = f2bf(p[1][r]);
            pw[row * 64 + ((c + 32) ^ swp)] = f2bf(p[2][r]);
            pw[row * 64 + ((c + 48) ^ swp)] = f2bf(p[3][r]);
        }
        const int swc = sw8(c) << 3;
        const short8_t pf0 = *(const short8_t*)&pw[c * 64 + ((g * 8) ^ swc)];
        const short8_t pf1 = *(const short8_t*)&pw[c * 64 + ((32 + g * 8) ^ swc)];
        __builtin_amdgcn_s_setprio(1);
#pragma unroll
        for (int cg = 0; cg < 4; ++cg) {
            const int vv = cg * 16 + c;
            const int swv = sw8(vv) << 3;
            const short8_t vf0 = *(const short8_t*)&lds_vt[vv * 64 + ((g * 8) ^ swv)];
            const short8_t vf1 = *(const short8_t*)&lds_vt[vv * 64 + ((32 + g * 8) ^ swv)];
            o[cg] = __builtin_amdgcn_mfma_f32_16x16x32_bf16(pf0, vf0, o[cg], 0, 0, 0);
            o[cg] = __builtin_amdgcn_mfma_f32_16x16x32_bf16(pf1, vf1, o[cg], 0, 0, 0);
        }
        __builtin_amdgcn_s_setprio(0);
        __syncthreads();
    }

#pragma unroll
    for (int r = 0; r < 4; ++r) {
        const float inv = 1.0f / l_run[r];
        float* orow = Op + ((size_t)bh * Sn + q0 + wave * 16 + g * 4 + r) * Dn + c;
#pragma unroll
        for (int cg = 0; cg < 4; ++cg) orow[cg * 16] = o[cg][r] * inv;
    }
}

extern "C" void kernel_launch(void* const* d_in, const int* in_sizes, int n_in,
                              void* d_out, int out_size, void* d_ws, size_t ws_size,
                              hipStream_t stream) {
    (void)in_sizes; (void)n_in; (void)out_size;
    const float* Q = (const float*)d_in[0];
    const float* K = (const float*)d_in[1];
    const float* V = (const float*)d_in[2];
    const void*  M = d_in[3];
    float* O = (float*)d_out;

    const size_t pmB = (size_t)Bn * Sn * MW * 8;            // 2 MB packed mask
    const size_t kvB = (size_t)Bn * Hn * Sn * Dn * 2;       // 16.78 MB each

    if (ws_size >= pmB + 2 * kvB) {
        unsigned long long* PM = (unsigned long long*)d_ws;
        unsigned short* Kb = (unsigned short*)((char*)d_ws + pmB);
        unsigned short* Vt = (unsigned short*)((char*)d_ws + pmB + kvB);
        convKV<<<dim3(Bn * Hn, NKT), 256, 0, stream>>>(K, V, M, Kb, Vt, PM);
        sdpa_v3<<<dim3(512), dim3(512), 0, stream>>>(Q, Kb, Vt, PM, O);
    } else {
        unsigned long long* PM = nullptr;
        if (ws_size >= pmB) {
            PM = (unsigned long long*)d_ws;
            pack_mask<<<1024, 256, 0, stream>>>(M, PM);
        }
        sdpa_v2<<<dim3(1024), dim3(512), 0, stream>>>(Q, K, V, M, PM, O);
    }
}